// Round 6
// baseline (287.812 us; speedup 1.0000x reference)
//
#include <hip/hip_runtime.h>

typedef unsigned short u16;
typedef __attribute__((ext_vector_type(8))) _Float16 f16x8;
typedef __attribute__((ext_vector_type(4))) float f32x4;

#define NT 256
#define BT 32      // lstm rows per block
#define CBT 32     // conv rows per block
#define A1S 152    // lstm A1 row stride (u16): feat 0..79 | h1old(->h2old) 80..143 | zero 144..151
#define H1S 72     // h1new row stride
#define CFS 68     // c-state LDS row stride (u16)

__device__ __forceinline__ u16 f2h(float f) {
  _Float16 h = (_Float16)f;
  union { _Float16 h; u16 u; } c; c.h = h; return c.u;
}
__device__ __forceinline__ float h2f(u16 v) {
  union { u16 u; _Float16 h; } c; c.u = v; return (float)c.h;
}
__device__ __forceinline__ float sigm(float x) { return 1.0f / (1.0f + __expf(-x)); }
__device__ __forceinline__ float tanh_(float x) {
  float ax = fabsf(x);
  float e = __expf(-2.0f * ax);
  float t = (1.0f - e) / (1.0f + e);
  return copysignf(t, x);
}
__device__ __forceinline__ uint2 packh4(float4 v) {
  return make_uint2((unsigned)f2h(v.x) | ((unsigned)f2h(v.y) << 16),
                    (unsigned)f2h(v.z) | ((unsigned)f2h(v.w) << 16));
}
__device__ __forceinline__ float4 unph4(uint2 p) {
  float4 r;
  r.x = h2f((u16)(p.x & 0xffff)); r.y = h2f((u16)(p.x >> 16));
  r.z = h2f((u16)(p.y & 0xffff)); r.w = h2f((u16)(p.y >> 16));
  return r;
}
// raw barrier: LDS ordering only, global stores/loads stay in flight (no vmcnt drain)
__device__ __forceinline__ void bar() {
  asm volatile("s_waitcnt lgkmcnt(0)" ::: "memory");
  __builtin_amdgcn_s_barrier();
  asm volatile("" ::: "memory");
}

// ---- d_ws layout ----
// u16 frag area (all f16): w1f[80 frags] | w2f[64] | wFf[8] | conv W frags[4] = 79872 u16
// byte 159744: bc f32[512] ; byte 161792: cf f32[89] ; byte 162176: feat[B][80] f16
#define WS_W1   0
#define WS_W2   40960
#define WS_FC1  73728
#define WS_CW   77824
#define WS_BOFF 159744
#define WS_CF   161792
#define WS_FEAT_U16 81088

// cf layout (f32): [0,16) pwhi | [16,32) pwlo | [32,48) pwb | [48,64) s1pb | [64,80) s2pb | [80,89) dw3x3

__global__ __launch_bounds__(NT) void prep(
    const float* __restrict__ wih1, const float* __restrict__ whh1,
    const float* __restrict__ wih2, const float* __restrict__ whh2,
    const float* __restrict__ fc1w,
    const float* __restrict__ bih1, const float* __restrict__ bhh1,
    const float* __restrict__ bih2, const float* __restrict__ bhh2,
    const float* __restrict__ dwWg, const float* __restrict__ pwWg, const float* __restrict__ pwBg,
    const float* __restrict__ s1dwg, const float* __restrict__ s1pwg, const float* __restrict__ s1pbg,
    const float* __restrict__ s2dwg, const float* __restrict__ s2pwg, const float* __restrict__ s2pbg,
    u16* __restrict__ wbf, float* __restrict__ bc, float* __restrict__ cf)
{
  int i = blockIdx.x * NT + threadIdx.x;
  if (i < 40960) {
    // w1 frag-linear: idx = (((g*4+wv)*5+kc)*64+l)*8+j8 ; value = w1cat[g*64+wv*16+(l&15)][kc*32+(l>>4)*8+j8]
    int j8 = i & 7, l = (i >> 3) & 63, rem = i >> 9;
    int kc = rem % 5, gw = rem / 5;
    int n = (gw >> 2) * 64 + (gw & 3) * 16 + (l & 15);
    int k = kc * 32 + (l >> 4) * 8 + j8;
    float v = 0.f;
    if (k < 80) v = wih1[n * 80 + k];
    else if (k < 144) v = whh1[n * 64 + (k - 80)];
    wbf[i] = f2h(v);
  } else if (i < 73728) {
    int t2 = i - 40960;
    int j8 = t2 & 7, l = (t2 >> 3) & 63, rem = t2 >> 9;
    int kc = rem & 3, gw = rem >> 2;
    int n = (gw >> 2) * 64 + (gw & 3) * 16 + (l & 15);
    int k = kc * 32 + (l >> 4) * 8 + j8;
    float v = (k < 64) ? wih2[n * 64 + k] : whh2[n * 64 + (k - 64)];
    wbf[i] = f2h(v);
  } else if (i < 77824) {
    int t2 = i - 73728;
    int j8 = t2 & 7, l = (t2 >> 3) & 63, rem = t2 >> 9;
    int kc = rem & 3, nt = rem >> 2;
    int n = nt * 16 + (l & 15);
    int k = kc * 32 + (l >> 4) * 8 + j8;
    int ks = (k < 64) ? k + 64 : k - 64;   // z=[h2|h1] -> ours [h1|h2]
    wbf[i] = f2h(fc1w[n * 128 + ks]);
  } else if (i < 79872) {
    // conv combined dw(x)pw weights, f16 B-frags: W[kk][co], kk=k*16+ci
    int t2 = i - 77824;
    int frag = t2 >> 9, u = t2 & 511;
    int j8 = u & 7, l = (u >> 3) & 63;
    int co = l & 15, kk = (l >> 4) * 8 + j8;
    float v = 0.f;
    if (frag == 0) { int k = kk >> 4, ci = kk & 15; v = s1dwg[ci * 3 + k] * s1pwg[co * 16 + ci]; }
    else if (frag == 1) { if (kk < 16) v = s1dwg[kk * 3 + 2] * s1pwg[co * 16 + kk]; }
    else if (frag == 2) { int k = kk >> 4, ci = kk & 15; v = s2dwg[ci * 3 + k] * s2pwg[co * 16 + ci]; }
    else { if (kk < 16) v = s2dwg[kk * 3 + 2] * s2pwg[co * 16 + kk]; }
    wbf[i] = f2h(v);
  }
  if (i < 256)      bc[i] = bih1[i] + bhh1[i];
  else if (i < 512) bc[i] = bih2[i - 256] + bhh2[i - 256];
  if (i < 89) {
    float v;
    if (i < 16)      { float w = pwWg[i];      v = w > 0.f ? w : 0.f; }
    else if (i < 32) { float w = pwWg[i - 16]; v = w > 0.f ? 0.f : w; }
    else if (i < 48) v = pwBg[i - 32];
    else if (i < 64) v = s1pbg[i - 48];
    else if (i < 80) v = s2pbg[i - 64];
    else             v = dwWg[i - 80];
    cf[i] = v;
  }
}

// ================= conv kernel (R2/R3-verified, unchanged) =================
#define CV_CW   0
#define CV_Y0   384
#define CV_XS   5504
#define CV_P    5504
#define CV_U1   5504
#define CV_FL   384
#define CV_SIZE 27008

__global__ __launch_bounds__(NT, 5) void convk(
    const float* __restrict__ xg, const u16* __restrict__ wbf,
    const float* __restrict__ cf, u16* __restrict__ featg)
{
  __shared__ __align__(16) unsigned char smem[CV_SIZE];
  const int t = threadIdx.x;
  const int blk = blockIdx.x;
  const int base = blk * CBT;

  float* cw = (float*)(smem + CV_CW);
  float* y0 = (float*)(smem + CV_Y0);
  float* xs = (float*)(smem + CV_XS);
  u16* pp  = (u16*)(smem + CV_P);
  u16* u1  = (u16*)(smem + CV_U1);
  u16* fl  = (u16*)(smem + CV_FL);

  const int lane = t & 63, wv = t >> 6, l15 = lane & 15, q16 = lane >> 4;

  const u16* Wf = wbf + WS_CW;
  f16x8 W1a = *(const f16x8*)(Wf + lane * 8);
  f16x8 W1b = *(const f16x8*)(Wf + 512 + lane * 8);
  f16x8 W2a = *(const f16x8*)(Wf + 1024 + lane * 8);
  f16x8 W2b = *(const f16x8*)(Wf + 1536 + lane * 8);

  if (t < 96) cw[t] = (t < 89) ? cf[t] : 0.f;
  {
    const float4* src = (const float4*)xg + (size_t)blk * 984;
    for (int i = t; i < 984; i += NT) *(float4*)(xs + i * 4) = src[i];
  }
  bar();

  // ---- stage A1: depthwise 3x3 -> y0 f32 ----
  {
    float d0 = cw[80], d1 = cw[81], d2 = cw[82], d3 = cw[83], d4 = cw[84],
          d5 = cw[85], d6 = cw[86], d7 = cw[87], d8 = cw[88];
    int b = t >> 3, w0 = (t & 7) * 5;
    const float* xb = xs + b * 123;
    float* yb = y0 + b * 40;
#pragma unroll
    for (int s = 0; s < 5; ++s) {
      int w = w0 + s;
      if (w < 39) {
        float v = d0 * xb[w]      + d1 * xb[w + 1]  + d2 * xb[w + 2]
                + d3 * xb[41 + w] + d4 * xb[42 + w] + d5 * xb[43 + w]
                + d6 * xb[82 + w] + d7 * xb[83 + w] + d8 * xb[84 + w];
        yb[w] = v;
      }
    }
  }
  bar();

  // ---- stage A2: pw+relu+maxpool (hi/lo trick) -> p f16 [32][21][16], cols 0 & 20 zero ----
  {
    uint4 z; z.x = z.y = z.z = z.w = 0u;
    if (t < 128) {
      int b = t >> 2, sub = t & 3;
      int col = (sub >> 1) ? 20 : 0;
      *(uint4*)(pp + (b * 21 + col) * 16 + (sub & 1) * 8) = z;
    }
    int b = t >> 3, u = t & 7, half = u >> 2, w5b = u & 3;
    float ph[8], pl[8], pb[8];
    ((float4*)ph)[0] = *(float4*)(cw + half * 8);
    ((float4*)ph)[1] = *(float4*)(cw + half * 8 + 4);
    ((float4*)pl)[0] = *(float4*)(cw + 16 + half * 8);
    ((float4*)pl)[1] = *(float4*)(cw + 16 + half * 8 + 4);
    ((float4*)pb)[0] = *(float4*)(cw + 32 + half * 8);
    ((float4*)pb)[1] = *(float4*)(cw + 32 + half * 8 + 4);
    const float* yb = y0 + b * 40;
#pragma unroll
    for (int s = 0; s < 5; ++s) {
      int w5 = w5b + s * 4;
      if (w5 < 19) {
        float a0 = yb[2 * w5], a1 = yb[2 * w5 + 1], a2 = yb[2 * w5 + 2];
        float mx = fmaxf(a0, fmaxf(a1, a2));
        float mn = fminf(a0, fminf(a1, a2));
        unsigned pk[4];
#pragma unroll
        for (int c = 0; c < 4; ++c) {
          float v0 = fmaxf(fmaf(ph[2 * c],     mx, fmaf(pl[2 * c],     mn, pb[2 * c])),     0.f);
          float v1 = fmaxf(fmaf(ph[2 * c + 1], mx, fmaf(pl[2 * c + 1], mn, pb[2 * c + 1])), 0.f);
          pk[c] = (unsigned)f2h(v0) | ((unsigned)f2h(v1) << 16);
        }
        uint4 st; st.x = pk[0]; st.y = pk[1]; st.z = pk[2]; st.w = pk[3];
        *(uint4*)(pp + (b * 21 + w5 + 1) * 16 + half * 8) = st;
      }
    }
  }
  bar();

  // ---- stage B: rows (b,q) x CW1[48x16] via 2 MFMA; accs held across barrier so u1 overlays p ----
  f32x4 acc5[5];
  {
    int kA = q16 >> 1, ciA = (q16 & 1) * 8;
#pragma unroll
    for (int s = 0; s < 5; ++s) {
      int tile = wv + s * 4;
      int rowA = tile * 16 + l15;
      int bA = rowA / 10, qA = rowA - bA * 10;
      f16x8 a0 = *(const f16x8*)(pp + (bA * 21 + 2 * qA + kA) * 16 + ciA);
      f16x8 a1 = *(const f16x8*)(pp + (bA * 21 + 2 * qA + 2) * 16 + ciA);
      f32x4 acc = {0.f, 0.f, 0.f, 0.f};
      acc = __builtin_amdgcn_mfma_f32_16x16x32_f16(a0, W1a, acc, 0, 0, 0);
      acc = __builtin_amdgcn_mfma_f32_16x16x32_f16(a1, W1b, acc, 0, 0, 0);
      acc5[s] = acc;
    }
  }
  bar();
  {
    if (t < 64) {
      uint4 z; z.x = z.y = z.z = z.w = 0u;
      *(uint4*)(u1 + ((t >> 1) * 11 + 10) * 16 + (t & 1) * 8) = z;
    }
    float sb1 = cw[48 + l15];
#pragma unroll
    for (int s = 0; s < 5; ++s) {
      int tile = wv + s * 4;
#pragma unroll
      for (int r = 0; r < 4; ++r) {
        int rowg = tile * 16 + q16 * 4 + r;
        int bC = rowg / 10, qC = rowg - bC * 10;
        u1[(bC * 11 + qC) * 16 + l15] = f2h(fmaxf(acc5[s][r] + sb1, 0.f));
      }
    }
  }
  bar();

  // ---- stage C: rows (b,r5) x CW2[48x16] via 2 MFMA, relu -> fl f16 ----
  {
    float sb2 = cw[64 + l15];
    int kA = q16 >> 1, ciA = (q16 & 1) * 8;
    for (int tile = wv; tile < 10; tile += 4) {
      int rowA = tile * 16 + l15;
      int bA = rowA / 5, rA = rowA - bA * 5;
      f16x8 a0 = *(const f16x8*)(u1 + (bA * 11 + 2 * rA + kA) * 16 + ciA);
      f16x8 a1 = *(const f16x8*)(u1 + (bA * 11 + 2 * rA + 2) * 16 + ciA);
      f32x4 acc = {0.f, 0.f, 0.f, 0.f};
      acc = __builtin_amdgcn_mfma_f32_16x16x32_f16(a0, W2a, acc, 0, 0, 0);
      acc = __builtin_amdgcn_mfma_f32_16x16x32_f16(a1, W2b, acc, 0, 0, 0);
#pragma unroll
      for (int r = 0; r < 4; ++r) {
        int rowg = tile * 16 + q16 * 4 + r;
        int bC = rowg / 5, rC = rowg - bC * 5;
        fl[bC * 80 + rC * 16 + l15] = f2h(fmaxf(acc[r] + sb2, 0.f));
      }
    }
  }
  bar();

  {
    const uint4* s4 = (const uint4*)fl;
    uint4* d4 = (uint4*)(featg + (size_t)base * 80);
    for (int i = t; i < 320; i += NT) d4[i] = s4[i];
  }
}

// ================= lstm + fc kernel (BT=32, 6 blocks/CU) =================
// LDS: sw[640 f32] @0 2560 | A1[32][152]+16B @2560 9760 | H1N[32][72] @12320 4608 |
//      c1f[32][68] @16928 4352 | c2f[32][68] @21280 4352  -> 25632 B
#define LO_B1   0
#define LO_B2   256
#define LO_FC1B 512
#define LO_FC2W 544
#define LO_FC2B 576
#define LR_A1   2560
#define LR_H1N  12320
#define LR_C1F  16928
#define LR_C2F  21280
#define LSMEM   25632

__global__ __launch_bounds__(NT, 6) void lstmk(
    const float* __restrict__ h1g, const float* __restrict__ c1g,
    const float* __restrict__ h2g, const float* __restrict__ c2g,
    const float* __restrict__ fc1bg, const float* __restrict__ fc2wg, const float* __restrict__ fc2bg,
    const u16* __restrict__ wbf, const float* __restrict__ bc, const u16* __restrict__ featg,
    float* __restrict__ out, int B)
{
  __shared__ __align__(16) unsigned char smem[LSMEM];
  const int t = threadIdx.x;
  const int blk = blockIdx.x;
  const int base = blk * BT;

  float* sw = (float*)smem;
  u16* A1  = (u16*)(smem + LR_A1);
  u16* H1N = (u16*)(smem + LR_H1N);
  u16* c1f = (u16*)(smem + LR_C1F);
  u16* c2f = (u16*)(smem + LR_C2F);

  float* probO = out;
  float* h1o = out + B;
  float* c1o = out + B + B * 64;
  float* h2o = out + B + B * 128;
  float* c2o = out + B + B * 192;

  const u16* w1f = wbf + WS_W1;
  const u16* w2f = wbf + WS_W2;
  const u16* wFf = wbf + WS_FC1;

  const int w = t >> 6, lane = t & 63, q = lane >> 4, l15 = lane & 15;
  const int j = w * 16 + l15;

  // ---- staging: ALL inputs as full-line float4 streams ----
  {
    const float4* c1src = (const float4*)c1g + (size_t)blk * 512;
    const float4* c2src = (const float4*)c2g + (size_t)blk * 512;
#pragma unroll
    for (int k = 0; k < 2; ++k) {
      int i = t + k * 256, row = i >> 4, c4 = (i & 15) * 4;
      *(uint2*)(c1f + row * CFS + c4) = packh4(c1src[i]);
      *(uint2*)(c2f + row * CFS + c4) = packh4(c2src[i]);
    }
  }
  // h2old prefetch into packed f16 regs (written to A1 after P7's reads retire)
  uint2 h2p[2];
  {
    const float4* hsrc = (const float4*)h2g + (size_t)blk * 512;
#pragma unroll
    for (int k = 0; k < 2; ++k) h2p[k] = packh4(hsrc[t + k * 256]);
  }
  for (int i = t; i < 512; i += NT) sw[i] = bc[i];
  for (int i = t; i < 32;  i += NT) sw[LO_FC1B + i] = fc1bg[i];
  for (int i = t; i < 32;  i += NT) sw[LO_FC2W + i] = fc2wg[i];
  if (t == 0) sw[LO_FC2B] = fc2bg[0];
  // feat (f16) -> A1 cols 0..79
  for (int i = t; i < 320; i += NT) {
    int m = i / 10, o = (i - m * 10) * 8;
    *(uint4*)(A1 + m * A1S + o) = *(const uint4*)(featg + (size_t)(base + m) * 80 + o);
  }
  // h1 fp32 -> A1 cols 80..143
  {
    const float4* hsrc = (const float4*)h1g + (size_t)blk * 512;
#pragma unroll
    for (int k = 0; k < 2; ++k) {
      int i = t + k * 256, m = i >> 4, j4 = (i & 15) * 4;
      *(uint2*)(A1 + m * A1S + 80 + j4) = packh4(hsrc[i]);
    }
  }
  // zero A1 cols 144..151 (P7 kc=4 reads them vs zero B-frag; stale LDS may hold NaN patterns)
  if (t < 32) {
    uint4 z; z.x = z.y = z.z = z.w = 0u;
    *(uint4*)(A1 + t * A1S + 144) = z;
  }
  if (t == 32) {  // tail: row 31 kc=4,q=3 reads 16B past row end
    uint4 z; z.x = z.y = z.z = z.w = 0u;
    *(uint4*)(A1 + 32 * A1S) = z;
  }
  bar();

  // ---- P7: lstm1 ----
  {
    f16x8 bf1[4][5];
#pragma unroll
    for (int g = 0; g < 4; ++g)
#pragma unroll
      for (int kc = 0; kc < 5; ++kc)
        bf1[g][kc] = *(const f16x8*)(w1f + (size_t)((((g * 4 + w) * 5 + kc) * 64) + lane) * 8);
    float bI = sw[LO_B1 + j], bF = sw[LO_B1 + 64 + j], bG = sw[LO_B1 + 128 + j], bO = sw[LO_B1 + 192 + j];

#pragma unroll 1
    for (int mt = 0; mt < 2; ++mt) {
      f32x4 acc[4];
#pragma unroll
      for (int g = 0; g < 4; ++g) { acc[g][0] = 0.f; acc[g][1] = 0.f; acc[g][2] = 0.f; acc[g][3] = 0.f; }
      const u16* aB = A1 + (mt * 16 + l15) * A1S + q * 8;
#pragma unroll
      for (int kc = 0; kc < 5; ++kc) {
        f16x8 af = *(const f16x8*)(aB + kc * 32);
#pragma unroll
        for (int g = 0; g < 4; ++g)
          acc[g] = __builtin_amdgcn_mfma_f32_16x16x32_f16(af, bf1[g][kc], acc[g], 0, 0, 0);
      }
#pragma unroll
      for (int r = 0; r < 4; ++r) {
        int m = mt * 16 + q * 4 + r;
        float iv = acc[0][r] + bI;
        float fv = acc[1][r] + bF;
        float gv = acc[2][r] + bG;
        float ov = acc[3][r] + bO;
        float cold = h2f(c1f[m * CFS + j]);
        float cn = sigm(fv) * cold + sigm(iv) * tanh_(gv);
        float hn = sigm(ov) * tanh_(cn);
        c1f[m * CFS + j] = f2h(cn);      // in-place; slot owned by this thread
        H1N[m * H1S + j] = f2h(hn);
      }
    }
  }
  bar();   // all A1 reads + H1N/c1f writes done

  // ---- h2old regs -> A1 cols 80..143 (h1old dead) ----
  {
#pragma unroll
    for (int k = 0; k < 2; ++k) {
      int i = t + k * 256, m = i >> 4, j4 = (i & 15) * 4;
      *(uint2*)(A1 + m * A1S + 80 + j4) = h2p[k];
    }
  }
  bar();

  // ---- P8: lstm2, A = [h1new (H1N) | h2old (A1 cols 80..143)]; h2new -> A1 cols 0..63 ----
  {
    f16x8 bf2[4][4];
#pragma unroll
    for (int g = 0; g < 4; ++g)
#pragma unroll
      for (int kc = 0; kc < 4; ++kc)
        bf2[g][kc] = *(const f16x8*)(w2f + (size_t)((((g * 4 + w) * 4 + kc) * 64) + lane) * 8);
    float bI = sw[LO_B2 + j], bF = sw[LO_B2 + 64 + j], bG = sw[LO_B2 + 128 + j], bO = sw[LO_B2 + 192 + j];

#pragma unroll 1
    for (int mt = 0; mt < 2; ++mt) {
      f32x4 acc[4];
#pragma unroll
      for (int g = 0; g < 4; ++g) { acc[g][0] = 0.f; acc[g][1] = 0.f; acc[g][2] = 0.f; acc[g][3] = 0.f; }
      const u16* aB1 = H1N + (mt * 16 + l15) * H1S + q * 8;
      const u16* aB2 = A1 + (mt * 16 + l15) * A1S + 80 + q * 8;
#pragma unroll
      for (int kc = 0; kc < 4; ++kc) {
        f16x8 af = (kc < 2) ? *(const f16x8*)(aB1 + kc * 32)
                            : *(const f16x8*)(aB2 + (kc - 2) * 32);
#pragma unroll
        for (int g = 0; g < 4; ++g)
          acc[g] = __builtin_amdgcn_mfma_f32_16x16x32_f16(af, bf2[g][kc], acc[g], 0, 0, 0);
      }
#pragma unroll
      for (int r = 0; r < 4; ++r) {
        int m = mt * 16 + q * 4 + r;
        float iv = acc[0][r] + bI;
        float fv = acc[1][r] + bF;
        float gv = acc[2][r] + bG;
        float ov = acc[3][r] + bO;
        float cold = h2f(c2f[m * CFS + j]);
        float cn = sigm(fv) * cold + sigm(iv) * tanh_(gv);
        float hn = sigm(ov) * tanh_(cn);
        c2f[m * CFS + j] = f2h(cn);
        A1[m * A1S + j] = f2h(hn);       // h2new, cols 0..63 (feat dead)
      }
    }
  }
  bar();

  // ---- tail, wave-split: waves 0-1 fc1+fc2; waves 2-3 output conversion stores ----
  if (w < 2) {
    f32x4 accf[2];
#pragma unroll
    for (int nt = 0; nt < 2; ++nt) { accf[nt][0] = 0.f; accf[nt][1] = 0.f; accf[nt][2] = 0.f; accf[nt][3] = 0.f; }
    int m0 = w * 16;
#pragma unroll
    for (int kc = 0; kc < 4; ++kc) {
      f16x8 a = (kc < 2)
        ? *(const f16x8*)(H1N + (m0 + l15) * H1S + kc * 32 + q * 8)
        : *(const f16x8*)(A1 + (m0 + l15) * A1S + (kc - 2) * 32 + q * 8);
#pragma unroll
      for (int nt = 0; nt < 2; ++nt) {
        f16x8 bfr = *(const f16x8*)(wFf + (size_t)(((nt * 4 + kc) * 64) + lane) * 8);
        accf[nt] = __builtin_amdgcn_mfma_f32_16x16x32_f16(a, bfr, accf[nt], 0, 0, 0);
      }
    }
    // fc2: z-row lives across the 16 lanes of this l15-group (2 n's per lane); butterfly-reduce
    float fw0 = sw[LO_FC2W + l15], fw1 = sw[LO_FC2W + 16 + l15];
    float fb0 = sw[LO_FC1B + l15], fb1 = sw[LO_FC1B + 16 + l15];
    float f2b = sw[LO_FC2B];
#pragma unroll
    for (int r = 0; r < 4; ++r) {
      float zv0 = fmaxf(accf[0][r] + fb0, 0.f);
      float zv1 = fmaxf(accf[1][r] + fb1, 0.f);
      float part = fmaf(zv0, fw0, zv1 * fw1);
      part += __shfl_xor(part, 1);
      part += __shfl_xor(part, 2);
      part += __shfl_xor(part, 4);
      part += __shfl_xor(part, 8);
      if (l15 == 0) probO[base + m0 + q * 4 + r] = sigm(part + f2b);
    }
  } else {
    int u = t - 128;
#pragma unroll
    for (int k = 0; k < 4; ++k) {
      int i = u + k * 128, row = i >> 4, c4 = (i & 15) * 4;
      size_t gb = (size_t)(base + row) * 64 + c4;
      *(float4*)(h1o + gb) = unph4(*(const uint2*)(H1N + row * H1S + c4));
      *(float4*)(c1o + gb) = unph4(*(const uint2*)(c1f + row * CFS + c4));
      *(float4*)(h2o + gb) = unph4(*(const uint2*)(A1 + row * A1S + c4));
      *(float4*)(c2o + gb) = unph4(*(const uint2*)(c2f + row * CFS + c4));
    }
  }
}

extern "C" void kernel_launch(void* const* d_in, const int* in_sizes, int n_in,
                              void* d_out, int out_size, void* d_ws, size_t ws_size,
                              hipStream_t stream) {
  (void)n_in; (void)out_size; (void)ws_size;
  int B = in_sizes[0] / 123;
  u16* wbf = (u16*)d_ws;
  float* bcm = (float*)((char*)d_ws + WS_BOFF);
  float* cfm = (float*)((char*)d_ws + WS_CF);
  u16* featg = (u16*)d_ws + WS_FEAT_U16;

  hipLaunchKernelGGL(prep, dim3(312), dim3(NT), 0, stream,
      (const float*)d_in[14], (const float*)d_in[15],
      (const float*)d_in[18], (const float*)d_in[19],
      (const float*)d_in[22],
      (const float*)d_in[16], (const float*)d_in[17],
      (const float*)d_in[20], (const float*)d_in[21],
      (const float*)d_in[5], (const float*)d_in[6], (const float*)d_in[7],
      (const float*)d_in[8], (const float*)d_in[9], (const float*)d_in[10],
      (const float*)d_in[11], (const float*)d_in[12], (const float*)d_in[13],
      wbf, bcm, cfm);

  hipLaunchKernelGGL(convk, dim3(B / CBT), dim3(NT), 0, stream,
      (const float*)d_in[0], wbf, cfm, featg);

  hipLaunchKernelGGL(lstmk, dim3(B / BT), dim3(NT), 0, stream,
      (const float*)d_in[1], (const float*)d_in[2],
      (const float*)d_in[3], (const float*)d_in[4],
      (const float*)d_in[23], (const float*)d_in[24], (const float*)d_in[25],
      wbf, bcm, featg,
      (float*)d_out, B);
}

// Round 7
// 228.254 us; speedup vs baseline: 1.2609x; 1.2609x over previous
//
#include <hip/hip_runtime.h>

typedef unsigned short u16;
typedef __attribute__((ext_vector_type(8))) _Float16 f16x8;
typedef __attribute__((ext_vector_type(4))) float f32x4;

#define NT 256
#define BT 32      // lstm rows per block
#define CBT 32     // conv rows per block
#define A1S 152    // lstm A1 row stride (u16): feat 0..79 | h1old(->h2old) 80..143 | zero 144..151
#define H1S 72     // h1new row stride
#define CFS 68     // c-state LDS row stride (u16)

__device__ __forceinline__ u16 f2h(float f) {
  _Float16 h = (_Float16)f;
  union { _Float16 h; u16 u; } c; c.h = h; return c.u;
}
__device__ __forceinline__ float h2f(u16 v) {
  union { u16 u; _Float16 h; } c; c.u = v; return (float)c.h;
}
__device__ __forceinline__ float sigm(float x) { return 1.0f / (1.0f + __expf(-x)); }
__device__ __forceinline__ float tanh_(float x) {
  float ax = fabsf(x);
  float e = __expf(-2.0f * ax);
  float t = (1.0f - e) / (1.0f + e);
  return copysignf(t, x);
}
__device__ __forceinline__ uint2 packh4(float4 v) {
  return make_uint2((unsigned)f2h(v.x) | ((unsigned)f2h(v.y) << 16),
                    (unsigned)f2h(v.z) | ((unsigned)f2h(v.w) << 16));
}
__device__ __forceinline__ float4 unph4(uint2 p) {
  float4 r;
  r.x = h2f((u16)(p.x & 0xffff)); r.y = h2f((u16)(p.x >> 16));
  r.z = h2f((u16)(p.y & 0xffff)); r.w = h2f((u16)(p.y >> 16));
  return r;
}
// raw barrier: LDS ordering only, global stores/loads stay in flight (no vmcnt drain)
__device__ __forceinline__ void bar() {
  asm volatile("s_waitcnt lgkmcnt(0)" ::: "memory");
  __builtin_amdgcn_s_barrier();
  asm volatile("" ::: "memory");
}

// ---- d_ws layout ----
// u16 frag area (all f16): w1f[80 frags] | w2f[64] | wFf[8] | conv W frags[4] = 79872 u16
// byte 159744: bc f32[512] ; byte 161792: cf f32[89] ; byte 162176: feat[B][80] f16
#define WS_W1   0
#define WS_W2   40960
#define WS_FC1  73728
#define WS_CW   77824
#define WS_BOFF 159744
#define WS_CF   161792
#define WS_FEAT_U16 81088

// cf layout (f32): [0,16) pwhi | [16,32) pwlo | [32,48) pwb | [48,64) s1pb | [64,80) s2pb | [80,89) dw3x3

__global__ __launch_bounds__(NT) void prep(
    const float* __restrict__ wih1, const float* __restrict__ whh1,
    const float* __restrict__ wih2, const float* __restrict__ whh2,
    const float* __restrict__ fc1w,
    const float* __restrict__ bih1, const float* __restrict__ bhh1,
    const float* __restrict__ bih2, const float* __restrict__ bhh2,
    const float* __restrict__ dwWg, const float* __restrict__ pwWg, const float* __restrict__ pwBg,
    const float* __restrict__ s1dwg, const float* __restrict__ s1pwg, const float* __restrict__ s1pbg,
    const float* __restrict__ s2dwg, const float* __restrict__ s2pwg, const float* __restrict__ s2pbg,
    u16* __restrict__ wbf, float* __restrict__ bc, float* __restrict__ cf)
{
  int i = blockIdx.x * NT + threadIdx.x;
  if (i < 40960) {
    // w1 frag-linear: idx = (((g*4+wv)*5+kc)*64+l)*8+j8 ; value = w1cat[g*64+wv*16+(l&15)][kc*32+(l>>4)*8+j8]
    int j8 = i & 7, l = (i >> 3) & 63, rem = i >> 9;
    int kc = rem % 5, gw = rem / 5;
    int n = (gw >> 2) * 64 + (gw & 3) * 16 + (l & 15);
    int k = kc * 32 + (l >> 4) * 8 + j8;
    float v = 0.f;
    if (k < 80) v = wih1[n * 80 + k];
    else if (k < 144) v = whh1[n * 64 + (k - 80)];
    wbf[i] = f2h(v);
  } else if (i < 73728) {
    int t2 = i - 40960;
    int j8 = t2 & 7, l = (t2 >> 3) & 63, rem = t2 >> 9;
    int kc = rem & 3, gw = rem >> 2;
    int n = (gw >> 2) * 64 + (gw & 3) * 16 + (l & 15);
    int k = kc * 32 + (l >> 4) * 8 + j8;
    float v = (k < 64) ? wih2[n * 64 + k] : whh2[n * 64 + (k - 64)];
    wbf[i] = f2h(v);
  } else if (i < 77824) {
    int t2 = i - 73728;
    int j8 = t2 & 7, l = (t2 >> 3) & 63, rem = t2 >> 9;
    int kc = rem & 3, nt = rem >> 2;
    int n = nt * 16 + (l & 15);
    int k = kc * 32 + (l >> 4) * 8 + j8;
    int ks = (k < 64) ? k + 64 : k - 64;   // z=[h2|h1] -> ours [h1|h2]
    wbf[i] = f2h(fc1w[n * 128 + ks]);
  } else if (i < 79872) {
    // conv combined dw(x)pw weights, f16 B-frags: W[kk][co], kk=k*16+ci
    int t2 = i - 77824;
    int frag = t2 >> 9, u = t2 & 511;
    int j8 = u & 7, l = (u >> 3) & 63;
    int co = l & 15, kk = (l >> 4) * 8 + j8;
    float v = 0.f;
    if (frag == 0) { int k = kk >> 4, ci = kk & 15; v = s1dwg[ci * 3 + k] * s1pwg[co * 16 + ci]; }
    else if (frag == 1) { if (kk < 16) v = s1dwg[kk * 3 + 2] * s1pwg[co * 16 + kk]; }
    else if (frag == 2) { int k = kk >> 4, ci = kk & 15; v = s2dwg[ci * 3 + k] * s2pwg[co * 16 + ci]; }
    else { if (kk < 16) v = s2dwg[kk * 3 + 2] * s2pwg[co * 16 + kk]; }
    wbf[i] = f2h(v);
  }
  if (i < 256)      bc[i] = bih1[i] + bhh1[i];
  else if (i < 512) bc[i] = bih2[i - 256] + bhh2[i - 256];
  if (i < 89) {
    float v;
    if (i < 16)      { float w = pwWg[i];      v = w > 0.f ? w : 0.f; }
    else if (i < 32) { float w = pwWg[i - 16]; v = w > 0.f ? 0.f : w; }
    else if (i < 48) v = pwBg[i - 32];
    else if (i < 64) v = s1pbg[i - 48];
    else if (i < 80) v = s2pbg[i - 64];
    else             v = dwWg[i - 80];
    cf[i] = v;
  }
}

// ================= conv kernel (R2/R3-verified, unchanged) =================
#define CV_CW   0
#define CV_Y0   384
#define CV_XS   5504
#define CV_P    5504
#define CV_U1   5504
#define CV_FL   384
#define CV_SIZE 27008

__global__ __launch_bounds__(NT, 5) void convk(
    const float* __restrict__ xg, const u16* __restrict__ wbf,
    const float* __restrict__ cf, u16* __restrict__ featg)
{
  __shared__ __align__(16) unsigned char smem[CV_SIZE];
  const int t = threadIdx.x;
  const int blk = blockIdx.x;
  const int base = blk * CBT;

  float* cw = (float*)(smem + CV_CW);
  float* y0 = (float*)(smem + CV_Y0);
  float* xs = (float*)(smem + CV_XS);
  u16* pp  = (u16*)(smem + CV_P);
  u16* u1  = (u16*)(smem + CV_U1);
  u16* fl  = (u16*)(smem + CV_FL);

  const int lane = t & 63, wv = t >> 6, l15 = lane & 15, q16 = lane >> 4;

  const u16* Wf = wbf + WS_CW;
  f16x8 W1a = *(const f16x8*)(Wf + lane * 8);
  f16x8 W1b = *(const f16x8*)(Wf + 512 + lane * 8);
  f16x8 W2a = *(const f16x8*)(Wf + 1024 + lane * 8);
  f16x8 W2b = *(const f16x8*)(Wf + 1536 + lane * 8);

  if (t < 96) cw[t] = (t < 89) ? cf[t] : 0.f;
  {
    const float4* src = (const float4*)xg + (size_t)blk * 984;
    for (int i = t; i < 984; i += NT) *(float4*)(xs + i * 4) = src[i];
  }
  bar();

  // ---- stage A1: depthwise 3x3 -> y0 f32 ----
  {
    float d0 = cw[80], d1 = cw[81], d2 = cw[82], d3 = cw[83], d4 = cw[84],
          d5 = cw[85], d6 = cw[86], d7 = cw[87], d8 = cw[88];
    int b = t >> 3, w0 = (t & 7) * 5;
    const float* xb = xs + b * 123;
    float* yb = y0 + b * 40;
#pragma unroll
    for (int s = 0; s < 5; ++s) {
      int w = w0 + s;
      if (w < 39) {
        float v = d0 * xb[w]      + d1 * xb[w + 1]  + d2 * xb[w + 2]
                + d3 * xb[41 + w] + d4 * xb[42 + w] + d5 * xb[43 + w]
                + d6 * xb[82 + w] + d7 * xb[83 + w] + d8 * xb[84 + w];
        yb[w] = v;
      }
    }
  }
  bar();

  // ---- stage A2: pw+relu+maxpool (hi/lo trick) -> p f16 [32][21][16], cols 0 & 20 zero ----
  {
    uint4 z; z.x = z.y = z.z = z.w = 0u;
    if (t < 128) {
      int b = t >> 2, sub = t & 3;
      int col = (sub >> 1) ? 20 : 0;
      *(uint4*)(pp + (b * 21 + col) * 16 + (sub & 1) * 8) = z;
    }
    int b = t >> 3, u = t & 7, half = u >> 2, w5b = u & 3;
    float ph[8], pl[8], pb[8];
    ((float4*)ph)[0] = *(float4*)(cw + half * 8);
    ((float4*)ph)[1] = *(float4*)(cw + half * 8 + 4);
    ((float4*)pl)[0] = *(float4*)(cw + 16 + half * 8);
    ((float4*)pl)[1] = *(float4*)(cw + 16 + half * 8 + 4);
    ((float4*)pb)[0] = *(float4*)(cw + 32 + half * 8);
    ((float4*)pb)[1] = *(float4*)(cw + 32 + half * 8 + 4);
    const float* yb = y0 + b * 40;
#pragma unroll
    for (int s = 0; s < 5; ++s) {
      int w5 = w5b + s * 4;
      if (w5 < 19) {
        float a0 = yb[2 * w5], a1 = yb[2 * w5 + 1], a2 = yb[2 * w5 + 2];
        float mx = fmaxf(a0, fmaxf(a1, a2));
        float mn = fminf(a0, fminf(a1, a2));
        unsigned pk[4];
#pragma unroll
        for (int c = 0; c < 4; ++c) {
          float v0 = fmaxf(fmaf(ph[2 * c],     mx, fmaf(pl[2 * c],     mn, pb[2 * c])),     0.f);
          float v1 = fmaxf(fmaf(ph[2 * c + 1], mx, fmaf(pl[2 * c + 1], mn, pb[2 * c + 1])), 0.f);
          pk[c] = (unsigned)f2h(v0) | ((unsigned)f2h(v1) << 16);
        }
        uint4 st; st.x = pk[0]; st.y = pk[1]; st.z = pk[2]; st.w = pk[3];
        *(uint4*)(pp + (b * 21 + w5 + 1) * 16 + half * 8) = st;
      }
    }
  }
  bar();

  // ---- stage B: rows (b,q) x CW1[48x16] via 2 MFMA; accs held across barrier so u1 overlays p ----
  f32x4 acc5[5];
  {
    int kA = q16 >> 1, ciA = (q16 & 1) * 8;
#pragma unroll
    for (int s = 0; s < 5; ++s) {
      int tile = wv + s * 4;
      int rowA = tile * 16 + l15;
      int bA = rowA / 10, qA = rowA - bA * 10;
      f16x8 a0 = *(const f16x8*)(pp + (bA * 21 + 2 * qA + kA) * 16 + ciA);
      f16x8 a1 = *(const f16x8*)(pp + (bA * 21 + 2 * qA + 2) * 16 + ciA);
      f32x4 acc = {0.f, 0.f, 0.f, 0.f};
      acc = __builtin_amdgcn_mfma_f32_16x16x32_f16(a0, W1a, acc, 0, 0, 0);
      acc = __builtin_amdgcn_mfma_f32_16x16x32_f16(a1, W1b, acc, 0, 0, 0);
      acc5[s] = acc;
    }
  }
  bar();
  {
    if (t < 64) {
      uint4 z; z.x = z.y = z.z = z.w = 0u;
      *(uint4*)(u1 + ((t >> 1) * 11 + 10) * 16 + (t & 1) * 8) = z;
    }
    float sb1 = cw[48 + l15];
#pragma unroll
    for (int s = 0; s < 5; ++s) {
      int tile = wv + s * 4;
#pragma unroll
      for (int r = 0; r < 4; ++r) {
        int rowg = tile * 16 + q16 * 4 + r;
        int bC = rowg / 10, qC = rowg - bC * 10;
        u1[(bC * 11 + qC) * 16 + l15] = f2h(fmaxf(acc5[s][r] + sb1, 0.f));
      }
    }
  }
  bar();

  // ---- stage C: rows (b,r5) x CW2[48x16] via 2 MFMA, relu -> fl f16 ----
  {
    float sb2 = cw[64 + l15];
    int kA = q16 >> 1, ciA = (q16 & 1) * 8;
    for (int tile = wv; tile < 10; tile += 4) {
      int rowA = tile * 16 + l15;
      int bA = rowA / 5, rA = rowA - bA * 5;
      f16x8 a0 = *(const f16x8*)(u1 + (bA * 11 + 2 * rA + kA) * 16 + ciA);
      f16x8 a1 = *(const f16x8*)(u1 + (bA * 11 + 2 * rA + 2) * 16 + ciA);
      f32x4 acc = {0.f, 0.f, 0.f, 0.f};
      acc = __builtin_amdgcn_mfma_f32_16x16x32_f16(a0, W2a, acc, 0, 0, 0);
      acc = __builtin_amdgcn_mfma_f32_16x16x32_f16(a1, W2b, acc, 0, 0, 0);
#pragma unroll
      for (int r = 0; r < 4; ++r) {
        int rowg = tile * 16 + q16 * 4 + r;
        int bC = rowg / 5, rC = rowg - bC * 5;
        fl[bC * 80 + rC * 16 + l15] = f2h(fmaxf(acc[r] + sb2, 0.f));
      }
    }
  }
  bar();

  {
    const uint4* s4 = (const uint4*)fl;
    uint4* d4 = (uint4*)(featg + (size_t)base * 80);
    for (int i = t; i < 320; i += NT) d4[i] = s4[i];
  }
}

// ================= lstm + fc kernel (BT=32, 4 blocks/CU, no spill) =================
// LDS: sw[640 f32] @0 2560 | A1[32][152]+16B @2560 9760 | H1N[32][72] @12320 4608 |
//      c1f[32][68] @16928 4352 | c2f[32][68] @21280 4352  -> 25632 B
#define LO_B1   0
#define LO_B2   256
#define LO_FC1B 512
#define LO_FC2W 544
#define LO_FC2B 576
#define LR_A1   2560
#define LR_H1N  12320
#define LR_C1F  16928
#define LR_C2F  21280
#define LSMEM   25632

__global__ __launch_bounds__(NT, 4) void lstmk(
    const float* __restrict__ h1g, const float* __restrict__ c1g,
    const float* __restrict__ h2g, const float* __restrict__ c2g,
    const float* __restrict__ fc1bg, const float* __restrict__ fc2wg, const float* __restrict__ fc2bg,
    const u16* __restrict__ wbf, const float* __restrict__ bc, const u16* __restrict__ featg,
    float* __restrict__ out, int B)
{
  __shared__ __align__(16) unsigned char smem[LSMEM];
  const int t = threadIdx.x;
  const int blk = blockIdx.x;
  const int base = blk * BT;

  float* sw = (float*)smem;
  u16* A1  = (u16*)(smem + LR_A1);
  u16* H1N = (u16*)(smem + LR_H1N);
  u16* c1f = (u16*)(smem + LR_C1F);
  u16* c2f = (u16*)(smem + LR_C2F);

  float* probO = out;
  float* h1o = out + B;
  float* c1o = out + B + B * 64;
  float* h2o = out + B + B * 128;
  float* c2o = out + B + B * 192;

  const u16* w1f = wbf + WS_W1;
  const u16* w2f = wbf + WS_W2;
  const u16* wFf = wbf + WS_FC1;

  const int w = t >> 6, lane = t & 63, q = lane >> 4, l15 = lane & 15;
  const int j = w * 16 + l15;

  // ---- staging: ALL inputs as full-line float4 streams ----
  {
    const float4* c1src = (const float4*)c1g + (size_t)blk * 512;
    const float4* c2src = (const float4*)c2g + (size_t)blk * 512;
#pragma unroll
    for (int k = 0; k < 2; ++k) {
      int i = t + k * 256, row = i >> 4, c4 = (i & 15) * 4;
      *(uint2*)(c1f + row * CFS + c4) = packh4(c1src[i]);
      *(uint2*)(c2f + row * CFS + c4) = packh4(c2src[i]);
    }
  }
  // h2old prefetch into packed f16 regs (written to A1 after P7's reads retire)
  uint2 h2p[2];
  {
    const float4* hsrc = (const float4*)h2g + (size_t)blk * 512;
#pragma unroll
    for (int k = 0; k < 2; ++k) h2p[k] = packh4(hsrc[t + k * 256]);
  }
  for (int i = t; i < 512; i += NT) sw[i] = bc[i];
  for (int i = t; i < 32;  i += NT) sw[LO_FC1B + i] = fc1bg[i];
  for (int i = t; i < 32;  i += NT) sw[LO_FC2W + i] = fc2wg[i];
  if (t == 0) sw[LO_FC2B] = fc2bg[0];
  // feat (f16) -> A1 cols 0..79
  for (int i = t; i < 320; i += NT) {
    int m = i / 10, o = (i - m * 10) * 8;
    *(uint4*)(A1 + m * A1S + o) = *(const uint4*)(featg + (size_t)(base + m) * 80 + o);
  }
  // h1 fp32 -> A1 cols 80..143
  {
    const float4* hsrc = (const float4*)h1g + (size_t)blk * 512;
#pragma unroll
    for (int k = 0; k < 2; ++k) {
      int i = t + k * 256, m = i >> 4, j4 = (i & 15) * 4;
      *(uint2*)(A1 + m * A1S + 80 + j4) = packh4(hsrc[i]);
    }
  }
  // zero A1 cols 144..151 (P7 kc=4 reads them vs zero B-frag; stale LDS may hold NaN patterns)
  if (t < 32) {
    uint4 z; z.x = z.y = z.z = z.w = 0u;
    *(uint4*)(A1 + t * A1S + 144) = z;
  }
  if (t == 32) {  // tail: row 31 kc=4,q=3 reads 16B past row end
    uint4 z; z.x = z.y = z.z = z.w = 0u;
    *(uint4*)(A1 + 32 * A1S) = z;
  }
  bar();

  // ---- P7: lstm1 ----
  {
    f16x8 bf1[4][5];
#pragma unroll
    for (int g = 0; g < 4; ++g)
#pragma unroll
      for (int kc = 0; kc < 5; ++kc)
        bf1[g][kc] = *(const f16x8*)(w1f + (size_t)((((g * 4 + w) * 5 + kc) * 64) + lane) * 8);
    float bI = sw[LO_B1 + j], bF = sw[LO_B1 + 64 + j], bG = sw[LO_B1 + 128 + j], bO = sw[LO_B1 + 192 + j];

#pragma unroll 1
    for (int mt = 0; mt < 2; ++mt) {
      f32x4 acc[4];
#pragma unroll
      for (int g = 0; g < 4; ++g) { acc[g][0] = 0.f; acc[g][1] = 0.f; acc[g][2] = 0.f; acc[g][3] = 0.f; }
      const u16* aB = A1 + (mt * 16 + l15) * A1S + q * 8;
#pragma unroll
      for (int kc = 0; kc < 5; ++kc) {
        f16x8 af = *(const f16x8*)(aB + kc * 32);
#pragma unroll
        for (int g = 0; g < 4; ++g)
          acc[g] = __builtin_amdgcn_mfma_f32_16x16x32_f16(af, bf1[g][kc], acc[g], 0, 0, 0);
      }
#pragma unroll
      for (int r = 0; r < 4; ++r) {
        int m = mt * 16 + q * 4 + r;
        float iv = acc[0][r] + bI;
        float fv = acc[1][r] + bF;
        float gv = acc[2][r] + bG;
        float ov = acc[3][r] + bO;
        float cold = h2f(c1f[m * CFS + j]);
        float cn = sigm(fv) * cold + sigm(iv) * tanh_(gv);
        float hn = sigm(ov) * tanh_(cn);
        c1f[m * CFS + j] = f2h(cn);      // in-place; slot owned by this thread
        H1N[m * H1S + j] = f2h(hn);
      }
    }
  }
  bar();   // all A1 reads + H1N/c1f writes done

  // ---- h2old regs -> A1 cols 80..143 (h1old dead) ----
  {
#pragma unroll
    for (int k = 0; k < 2; ++k) {
      int i = t + k * 256, m = i >> 4, j4 = (i & 15) * 4;
      *(uint2*)(A1 + m * A1S + 80 + j4) = h2p[k];
    }
  }
  bar();

  // ---- P8: lstm2, A = [h1new (H1N) | h2old (A1 cols 80..143)]; h2new -> A1 cols 0..63 ----
  {
    f16x8 bf2[4][4];
#pragma unroll
    for (int g = 0; g < 4; ++g)
#pragma unroll
      for (int kc = 0; kc < 4; ++kc)
        bf2[g][kc] = *(const f16x8*)(w2f + (size_t)((((g * 4 + w) * 4 + kc) * 64) + lane) * 8);
    float bI = sw[LO_B2 + j], bF = sw[LO_B2 + 64 + j], bG = sw[LO_B2 + 128 + j], bO = sw[LO_B2 + 192 + j];

#pragma unroll 1
    for (int mt = 0; mt < 2; ++mt) {
      f32x4 acc[4];
#pragma unroll
      for (int g = 0; g < 4; ++g) { acc[g][0] = 0.f; acc[g][1] = 0.f; acc[g][2] = 0.f; acc[g][3] = 0.f; }
      const u16* aB1 = H1N + (mt * 16 + l15) * H1S + q * 8;
      const u16* aB2 = A1 + (mt * 16 + l15) * A1S + 80 + q * 8;
#pragma unroll
      for (int kc = 0; kc < 4; ++kc) {
        f16x8 af = (kc < 2) ? *(const f16x8*)(aB1 + kc * 32)
                            : *(const f16x8*)(aB2 + (kc - 2) * 32);
#pragma unroll
        for (int g = 0; g < 4; ++g)
          acc[g] = __builtin_amdgcn_mfma_f32_16x16x32_f16(af, bf2[g][kc], acc[g], 0, 0, 0);
      }
#pragma unroll
      for (int r = 0; r < 4; ++r) {
        int m = mt * 16 + q * 4 + r;
        float iv = acc[0][r] + bI;
        float fv = acc[1][r] + bF;
        float gv = acc[2][r] + bG;
        float ov = acc[3][r] + bO;
        float cold = h2f(c2f[m * CFS + j]);
        float cn = sigm(fv) * cold + sigm(iv) * tanh_(gv);
        float hn = sigm(ov) * tanh_(cn);
        c2f[m * CFS + j] = f2h(cn);
        A1[m * A1S + j] = f2h(hn);       // h2new, cols 0..63 (feat dead)
      }
    }
  }
  bar();

  // ---- tail, wave-split: waves 0-1 fc1+fc2; waves 2-3 output conversion stores ----
  if (w < 2) {
    f32x4 accf[2];
#pragma unroll
    for (int nt = 0; nt < 2; ++nt) { accf[nt][0] = 0.f; accf[nt][1] = 0.f; accf[nt][2] = 0.f; accf[nt][3] = 0.f; }
    int m0 = w * 16;
#pragma unroll
    for (int kc = 0; kc < 4; ++kc) {
      f16x8 a = (kc < 2)
        ? *(const f16x8*)(H1N + (m0 + l15) * H1S + kc * 32 + q * 8)
        : *(const f16x8*)(A1 + (m0 + l15) * A1S + (kc - 2) * 32 + q * 8);
#pragma unroll
      for (int nt = 0; nt < 2; ++nt) {
        f16x8 bfr = *(const f16x8*)(wFf + (size_t)(((nt * 4 + kc) * 64) + lane) * 8);
        accf[nt] = __builtin_amdgcn_mfma_f32_16x16x32_f16(a, bfr, accf[nt], 0, 0, 0);
      }
    }
    // fc2: z-row lives across the 16 lanes of this l15-group (2 n's per lane); butterfly-reduce
    float fw0 = sw[LO_FC2W + l15], fw1 = sw[LO_FC2W + 16 + l15];
    float fb0 = sw[LO_FC1B + l15], fb1 = sw[LO_FC1B + 16 + l15];
    float f2b = sw[LO_FC2B];
#pragma unroll
    for (int r = 0; r < 4; ++r) {
      float zv0 = fmaxf(accf[0][r] + fb0, 0.f);
      float zv1 = fmaxf(accf[1][r] + fb1, 0.f);
      float part = fmaf(zv0, fw0, zv1 * fw1);
      part += __shfl_xor(part, 1);
      part += __shfl_xor(part, 2);
      part += __shfl_xor(part, 4);
      part += __shfl_xor(part, 8);
      if (l15 == 0) probO[base + m0 + q * 4 + r] = sigm(part + f2b);
    }
  } else {
    int u = t - 128;
#pragma unroll
    for (int k = 0; k < 4; ++k) {
      int i = u + k * 128, row = i >> 4, c4 = (i & 15) * 4;
      size_t gb = (size_t)(base + row) * 64 + c4;
      *(float4*)(h1o + gb) = unph4(*(const uint2*)(H1N + row * H1S + c4));
      *(float4*)(c1o + gb) = unph4(*(const uint2*)(c1f + row * CFS + c4));
      *(float4*)(h2o + gb) = unph4(*(const uint2*)(A1 + row * A1S + c4));
      *(float4*)(c2o + gb) = unph4(*(const uint2*)(c2f + row * CFS + c4));
    }
  }
}

extern "C" void kernel_launch(void* const* d_in, const int* in_sizes, int n_in,
                              void* d_out, int out_size, void* d_ws, size_t ws_size,
                              hipStream_t stream) {
  (void)n_in; (void)out_size; (void)ws_size;
  int B = in_sizes[0] / 123;
  u16* wbf = (u16*)d_ws;
  float* bcm = (float*)((char*)d_ws + WS_BOFF);
  float* cfm = (float*)((char*)d_ws + WS_CF);
  u16* featg = (u16*)d_ws + WS_FEAT_U16;

  hipLaunchKernelGGL(prep, dim3(312), dim3(NT), 0, stream,
      (const float*)d_in[14], (const float*)d_in[15],
      (const float*)d_in[18], (const float*)d_in[19],
      (const float*)d_in[22],
      (const float*)d_in[16], (const float*)d_in[17],
      (const float*)d_in[20], (const float*)d_in[21],
      (const float*)d_in[5], (const float*)d_in[6], (const float*)d_in[7],
      (const float*)d_in[8], (const float*)d_in[9], (const float*)d_in[10],
      (const float*)d_in[11], (const float*)d_in[12], (const float*)d_in[13],
      wbf, bcm, cfm);

  hipLaunchKernelGGL(convk, dim3(B / CBT), dim3(NT), 0, stream,
      (const float*)d_in[0], wbf, cfm, featg);

  hipLaunchKernelGGL(lstmk, dim3(B / BT), dim3(NT), 0, stream,
      (const float*)d_in[1], (const float*)d_in[2],
      (const float*)d_in[3], (const float*)d_in[4],
      (const float*)d_in[23], (const float*)d_in[24], (const float*)d_in[25],
      wbf, bcm, featg,
      (float*)d_out, B);
}